// Round 1
// baseline (25192.537 us; speedup 1.0000x reference)
//
#include <hip/hip_runtime.h>
#include <math.h>

constexpr int kB = 512;    // batch
constexpr int kT = 256;    // encoder length
constexpr int kH = 512;    // hidden
constexpr int kHor = 64;   // decoder horizon
constexpr int BT = 64;     // batch tile per block
constexpr int HT = 16;     // hidden units per block (64 gate rows)
constexpr int KB = 64;     // K tile
constexpr int LS = 68;     // padded LDS stride (68*4B = 272B = 16B-aligned rows)

__device__ __forceinline__ float sigmoidf_(float x) { return 1.0f / (1.0f + expf(-x)); }

// State buffers (h0,h1,c0,c1) are stored TRANSPOSED as (H, B): elem [j*kB + b].
// XMODE: 0 = layer1 (two GEMMs, no scalar input)
//        1 = scalar input from xvec[b*xstride]   (encoder layer0; xvec = x + t)
//        2 = scalar input from xvec[b]           (decoder layer0, t==0; xvec = inp)
//        3 = scalar input computed inline as head(h1prev) (decoder layer0 t>0);
//            in1 carries h1prev; block x==0 writes out column t-1.
template<int XMODE, bool TWO_GEMM>
__global__ __launch_bounds__(256) void lstm_step(
    const float* __restrict__ in1, const float* __restrict__ W1,
    const float* __restrict__ hprev, const float* __restrict__ W2,
    const float* __restrict__ bias,
    const float* __restrict__ xvec, int xstride,
    const float* __restrict__ wihcol,
    const float* __restrict__ headW, const float* __restrict__ headb,
    float* __restrict__ cbuf, float* __restrict__ hout,
    float* __restrict__ outcol)
{
    __shared__ float hs[KB][LS];   // h tile, k-major: hs[k][batch]
    __shared__ float wt[KB][LS];   // W tile, k-major: wt[k][4*jloc+gate]
    __shared__ float ph[4][BT];    // head partial sums (XMODE 3)

    const int tid = threadIdx.x;
    const int hh0 = blockIdx.x * HT;
    const int b0  = blockIdx.y * BT;
    const int jloc = tid >> 4;     // 0..15  hidden unit within tile
    const int bg   = tid & 15;     // 0..15  batch quad within tile
    const int j = hh0 + jloc;

    if (XMODE == 3) {
        // inp[b] = head_b + dot(h1prev[:,b], headW); 4 threads per batch elem
        const int part = tid >> 6, bl = tid & 63;
        float s = 0.f;
        const float* hp = in1 + b0 + bl;        // column of (H,B)
        const float* hw = headW + part * 128;
        #pragma unroll 8
        for (int k = 0; k < 128; ++k)
            s += hp[(part * 128 + k) * kB] * hw[k];
        ph[part][bl] = s;
        __syncthreads();
        if (blockIdx.x == 0 && tid < BT) {
            float v = headb[0] + ph[0][tid] + ph[1][tid] + ph[2][tid] + ph[3][tid];
            outcol[(b0 + tid) * kHor] = v;      // out column t-1
        }
    }

    float acc[4][4];
    #pragma unroll
    for (int g = 0; g < 4; ++g)
        #pragma unroll
        for (int i = 0; i < 4; ++i) acc[g][i] = 0.f;

    const int npass = TWO_GEMM ? 2 : 1;
    for (int pass = 0; pass < npass; ++pass) {
        const float* hsrc = (TWO_GEMM && pass == 0) ? in1 : hprev;
        const float* wsrc = (TWO_GEMM && pass == 0) ? W1  : W2;
        for (int kb = 0; kb < kH / KB; ++kb) {
            __syncthreads();
            // stage h tile: (H,B) global -> hs[k][b], no transpose needed
            #pragma unroll
            for (int it = 0; it < 4; ++it) {
                int id = tid + it * 256;
                int kk = id >> 4, bq = id & 15;
                float4 v = *(const float4*)(hsrc + (kb * KB + kk) * kB + b0 + 4 * bq);
                *(float4*)&hs[kk][4 * bq] = v;
            }
            // stage W tile: rows (gate*H + hh0 + jl), k-contiguous loads, transposed store
            #pragma unroll
            for (int it = 0; it < 4; ++it) {
                int id = tid + it * 256;
                int row = id >> 4, kq = id & 15;         // row 0..63
                int jl = row & 15, gate = row >> 4;
                float4 v = *(const float4*)(wsrc + (gate * kH + hh0 + jl) * kH + kb * KB + 4 * kq);
                wt[4 * kq + 0][4 * jl + gate] = v.x;
                wt[4 * kq + 1][4 * jl + gate] = v.y;
                wt[4 * kq + 2][4 * jl + gate] = v.z;
                wt[4 * kq + 3][4 * jl + gate] = v.w;
            }
            __syncthreads();
            #pragma unroll 4
            for (int k = 0; k < KB; ++k) {
                float4 hv = *(const float4*)&hs[k][4 * bg];
                float4 wv = *(const float4*)&wt[k][4 * jloc];
                float ha[4] = {hv.x, hv.y, hv.z, hv.w};
                float wa[4] = {wv.x, wv.y, wv.z, wv.w};
                #pragma unroll
                for (int g = 0; g < 4; ++g)
                    #pragma unroll
                    for (int i = 0; i < 4; ++i)
                        acc[g][i] += wa[g] * ha[i];
            }
        }
    }

    // ----- epilogue: bias + scalar-input term + LSTM cell -----
    const int bbase = b0 + 4 * bg;
    float xv[4];
    if (XMODE == 1) {
        #pragma unroll
        for (int i = 0; i < 4; ++i) xv[i] = xvec[(bbase + i) * xstride];
    } else if (XMODE == 2) {
        #pragma unroll
        for (int i = 0; i < 4; ++i) xv[i] = xvec[bbase + i];
    } else if (XMODE == 3) {
        #pragma unroll
        for (int i = 0; i < 4; ++i)
            xv[i] = headb[0] + ph[0][4 * bg + i] + ph[1][4 * bg + i]
                             + ph[2][4 * bg + i] + ph[3][4 * bg + i];
    }

    float bi[4], wc[4];
    #pragma unroll
    for (int g = 0; g < 4; ++g) {
        bi[g] = bias[g * kH + j];
        wc[g] = (XMODE != 0) ? wihcol[g * kH + j] : 0.f;
    }

    float4 cold = *(const float4*)(cbuf + j * kB + bbase);
    float cv[4] = {cold.x, cold.y, cold.z, cold.w};
    float cn[4], hn[4];
    #pragma unroll
    for (int i = 0; i < 4; ++i) {
        float xt = (XMODE != 0) ? xv[i] : 0.f;
        float gi = acc[0][i] + bi[0] + xt * wc[0];
        float gf = acc[1][i] + bi[1] + xt * wc[1];
        float gg = acc[2][i] + bi[2] + xt * wc[2];
        float go = acc[3][i] + bi[3] + xt * wc[3];
        float ig = sigmoidf_(gi);
        float fg = sigmoidf_(gf);
        float gv = tanhf(gg);
        float og = sigmoidf_(go);
        float c = fg * cv[i] + ig * gv;
        cn[i] = c;
        hn[i] = og * tanhf(c);
    }
    *(float4*)(cbuf + j * kB + bbase) = make_float4(cn[0], cn[1], cn[2], cn[3]);
    *(float4*)(hout + j * kB + bbase) = make_float4(hn[0], hn[1], hn[2], hn[3]);
}

__global__ __launch_bounds__(256) void init_kernel(
    const float* __restrict__ x, float* __restrict__ h0, float* __restrict__ c0,
    float* __restrict__ h1, float* __restrict__ c1, float* __restrict__ inp)
{
    int i = blockIdx.x * 256 + threadIdx.x;   // grid covers B*H
    h0[i] = 0.f; c0[i] = 0.f; h1[i] = 0.f; c1[i] = 0.f;
    if (i < kB) inp[i] = x[i * kT + (kT - 1)];   // x[:, T-1, 0]
}

__global__ __launch_bounds__(256) void head_kernel(
    const float* __restrict__ h1, const float* __restrict__ headW,
    const float* __restrict__ headb, float* __restrict__ outcol)
{
    int b = blockIdx.x * 256 + threadIdx.x;
    float s = headb[0];
    for (int k = 0; k < kH; ++k) s += h1[k * kB + b] * headW[k];
    outcol[b * kHor] = s;
}

extern "C" void kernel_launch(void* const* d_in, const int* in_sizes, int n_in,
                              void* d_out, int out_size, void* d_ws, size_t ws_size,
                              hipStream_t stream)
{
    const float* x     = (const float*)d_in[0];
    const float* eWih0 = (const float*)d_in[1];
    const float* eWhh0 = (const float*)d_in[2];
    const float* eb0   = (const float*)d_in[3];
    const float* eWih1 = (const float*)d_in[4];
    const float* eWhh1 = (const float*)d_in[5];
    const float* eb1   = (const float*)d_in[6];
    const float* dWih0 = (const float*)d_in[7];
    const float* dWhh0 = (const float*)d_in[8];
    const float* db0   = (const float*)d_in[9];
    const float* dWih1 = (const float*)d_in[10];
    const float* dWhh1 = (const float*)d_in[11];
    const float* db1   = (const float*)d_in[12];
    const float* hW    = (const float*)d_in[13];
    const float* hb    = (const float*)d_in[14];
    float* out = (float*)d_out;
    float* ws  = (float*)d_ws;

    const int HB = kH * kB;
    float* h0[2] = {ws, ws + HB};
    float* c0    = ws + 2 * HB;
    float* h1[2] = {ws + 3 * HB, ws + 4 * HB};
    float* c1    = ws + 5 * HB;
    float* inp   = ws + 6 * HB;

    init_kernel<<<dim3(HB / 256), 256, 0, stream>>>(x, h0[0], c0, h1[0], c1, inp);

    dim3 grid(kH / HT, kB / BT);   // (32, 8) = 256 blocks
    int cur = 0;

    // encoder
    for (int t = 0; t < kT; ++t) {
        lstm_step<1, false><<<grid, 256, 0, stream>>>(
            nullptr, nullptr, h0[cur], eWhh0, eb0,
            x + t, kT, eWih0, nullptr, nullptr,
            c0, h0[1 - cur], nullptr);
        lstm_step<0, true><<<grid, 256, 0, stream>>>(
            h0[1 - cur], eWih1, h1[cur], eWhh1, eb1,
            nullptr, 0, nullptr, nullptr, nullptr,
            c1, h1[1 - cur], nullptr);
        cur ^= 1;
    }

    // decoder
    for (int t = 0; t < kHor; ++t) {
        if (t == 0) {
            lstm_step<2, false><<<grid, 256, 0, stream>>>(
                nullptr, nullptr, h0[cur], dWhh0, db0,
                inp, 1, dWih0, nullptr, nullptr,
                c0, h0[1 - cur], nullptr);
        } else {
            lstm_step<3, false><<<grid, 256, 0, stream>>>(
                h1[cur], nullptr, h0[cur], dWhh0, db0,
                nullptr, 0, dWih0, hW, hb,
                c0, h0[1 - cur], out + (t - 1));
        }
        lstm_step<0, true><<<grid, 256, 0, stream>>>(
            h0[1 - cur], dWih1, h1[cur], dWhh1, db1,
            nullptr, 0, nullptr, nullptr, nullptr,
            c1, h1[1 - cur], nullptr);
        cur ^= 1;
    }

    head_kernel<<<dim3(kB / 256), 256, 0, stream>>>(h1[cur], hW, hb, out + (kHor - 1));
}

// Round 2
// 7727.622 us; speedup vs baseline: 3.2601x; 3.2601x over previous
//
#include <hip/hip_runtime.h>
#include <math.h>

using ushort_t = unsigned short;
using short8 = __attribute__((ext_vector_type(8))) short;
using floatx16 = __attribute__((ext_vector_type(16))) float;

constexpr int kB = 512, kT = 256, kH = 512, kHor = 64;
constexpr int NG = 4 * kH;  // 2048 packed gate rows

__device__ __forceinline__ ushort_t f2bf(float v) {
  unsigned u = __builtin_bit_cast(unsigned, v);
  return (ushort_t)((u + 0x7FFFu + ((u >> 16) & 1u)) >> 16);
}
__device__ __forceinline__ float bf2f(ushort_t b) {
  unsigned u = (unsigned)b << 16;
  return __builtin_bit_cast(float, u);
}
__device__ __forceinline__ float sig_(float x) { return 1.0f / (1.0f + __expf(-x)); }

__device__ __forceinline__ void async16(const ushort_t* g, ushort_t* l) {
  __builtin_amdgcn_global_load_lds(
      (const __attribute__((address_space(1))) void*)g,
      (__attribute__((address_space(3))) void*)l, 16, 0, 0);
}

struct UnitP {
  const ushort_t *Whi, *Wlo;            // packed weights [r=j*4+g][k], stride Kw
  const ushort_t *B0hi, *B0lo;          // h source planes (B,H), k 0..511
  const ushort_t *B1hi, *B1lo;          // k 512..1023 (unit B)
  const float* bias;                    // packed [j*4+g]
  float* c;                             // (H j, B n) fp32
  ushort_t *Hhi, *Hlo;                  // output h planes (B,H)
  int Kw;                               // 512 or 1024
};

struct KP {
  UnitP ua, ub;
  int nA;                               // blocks for unit A
  const float* xsrc; const float* wx; int xmode; int tcol;  // unit-A input term
  float* outp; int ocol;                // ocol>=0: out[:,ocol] = xsrc (inp mode)
  float* inp_next; const float* headb; int do_init;
  const float* headW; float* head_acc; int do_head;
};

// Block: 64 gate-rows x 64 batch, 4 waves of one 32x32 mfma tile each.
// LDS tile layout (per plane, 64 rows x 64 k): slot q = row*8 + (k8 ^ (row&7)),
// 16B per slot -> conflict-spread b128 reads, DMA-gather compatible.
__global__ __launch_bounds__(256) void lstm_mfma(KP P) {
  __shared__ __align__(16) ushort_t sm[32768];   // 2 buffers x 4 planes x 4096
  __shared__ ushort_t hshi[64 * 18];
  __shared__ ushort_t hslo[64 * 18];

  const int tid = threadIdx.x;
  const int bx = blockIdx.x;
  const bool isB = bx >= P.nA;
  const UnitP& U = isB ? P.ub : P.ua;
  const int bidx = isB ? bx - P.nA : bx;
  const int mb = bidx & 31;
  const int nb = bidx >> 5;
  const int m0blk = mb * 64;
  const int n0blk = nb * 64;
  const int nkt = U.Kw >> 6;

  const int wv = tid >> 6;
  const int ln = tid & 63;
  const int l31 = ln & 31;
  const int half = ln >> 5;
  const int wm = wv & 1, wn = wv >> 1;
  const int m0w = wm * 32, n0w = wn * 32;

  // staging invariants (wave wv stages plane wv: 0=Ahi 1=Alo 2=Bhi 3=Blo)
  const int r8 = ln >> 3;
  const int k8s = (ln & 7) ^ r8;
  const bool stA = wv < 2;
  const ushort_t* gsrcA = (wv == 0) ? U.Whi : U.Wlo;
  const ushort_t* b0p = (wv == 2) ? U.B0hi : U.B0lo;
  const ushort_t* b1p = (wv == 2) ? U.B1hi : U.B1lo;
  ushort_t* lwb = &sm[wv * 4096];

  auto issue = [&](int kt, int bufsel) {
    ushort_t* lb = lwb + bufsel * 16384;
    if (stA) {
      const ushort_t* g0 = gsrcA + (size_t)(m0blk + r8) * U.Kw + kt * 64 + k8s * 8;
      #pragma unroll
      for (int i = 0; i < 8; ++i)
        async16(g0 + (size_t)i * 8 * U.Kw, lb + i * 512);
    } else {
      const ushort_t* bsrc = (kt < 8) ? b0p : b1p;
      const int col0 = (kt & 7) * 64;
      const ushort_t* g0 = bsrc + (size_t)(n0blk + r8) * kH + col0 + k8s * 8;
      #pragma unroll
      for (int i = 0; i < 8; ++i)
        async16(g0 + (size_t)i * 8 * kH, lb + i * 512);
    }
  };

  floatx16 acc;
  #pragma unroll
  for (int i = 0; i < 16; ++i) acc[i] = 0.0f;

  issue(0, 0);

  for (int kt = 0; kt < nkt; ++kt) {
    const int cur = kt & 1;
    if (kt + 1 < nkt) {
      if (kt > 0) {           // WAR: everyone done computing buf[cur^1]
        asm volatile("" ::: "memory");
        __builtin_amdgcn_s_barrier();
        asm volatile("" ::: "memory");
      }
      issue(kt + 1, cur ^ 1);
      asm volatile("" ::: "memory");
      __builtin_amdgcn_s_waitcnt(0xF78);  // vmcnt(8): my cur-tile loads done
    } else {
      asm volatile("" ::: "memory");
      __builtin_amdgcn_s_waitcnt(0xF70);  // vmcnt(0)
    }
    asm volatile("" ::: "memory");
    __builtin_amdgcn_s_barrier();          // all waves' cur loads visible
    asm volatile("" ::: "memory");

    const ushort_t* base = &sm[cur * 16384];
    #pragma unroll
    for (int ks = 0; ks < 4; ++ks) {
      const int k8 = ks * 2 + half;
      const int qa = (m0w + l31) * 8 + (k8 ^ (l31 & 7));
      const int qb = (n0w + l31) * 8 + (k8 ^ (l31 & 7));
      short8 ahi = *(const short8*)(base + qa * 8);
      short8 alo = *(const short8*)(base + 4096 + qa * 8);
      short8 bhi = *(const short8*)(base + 8192 + qb * 8);
      short8 blo = *(const short8*)(base + 12288 + qb * 8);
      acc = __builtin_amdgcn_mfma_f32_32x32x16_bf16(alo, bhi, acc, 0, 0, 0);
      acc = __builtin_amdgcn_mfma_f32_32x32x16_bf16(ahi, blo, acc, 0, 0, 0);
      acc = __builtin_amdgcn_mfma_f32_32x32x16_bf16(ahi, bhi, acc, 0, 0, 0);
    }
  }

  // ---- epilogue: lane holds 4 j-groups x 4 gates for one n ----
  const int jt0 = mb * 16;
  const int ng = n0blk + n0w + l31;
  float xv = 0.0f;
  if (!isB) xv = (P.xmode == 0) ? P.xsrc[(size_t)ng * kT + P.tcol] : P.xsrc[ng];

  #pragma unroll
  for (int rg = 0; rg < 4; ++rg) {
    const int jl = wm * 8 + rg * 2 + half;      // j within block's 16
    const int jg = jt0 + jl;
    const float4 bi = *(const float4*)&U.bias[jg * 4];
    float gi = acc[rg * 4 + 0] + bi.x;
    float gf = acc[rg * 4 + 1] + bi.y;
    float gg = acc[rg * 4 + 2] + bi.z;
    float go = acc[rg * 4 + 3] + bi.w;
    if (!isB) {
      const float4 wx4 = *(const float4*)&P.wx[jg * 4];
      gi += xv * wx4.x; gf += xv * wx4.y; gg += xv * wx4.z; go += xv * wx4.w;
    }
    const float i_ = sig_(gi), f_ = sig_(gf), g_ = tanhf(gg), o_ = sig_(go);
    float* cp = U.c + (size_t)jg * kB + ng;
    const float cn = f_ * (*cp) + i_ * g_;
    *cp = cn;
    const float hn = o_ * tanhf(cn);
    const ushort_t hhi = f2bf(hn);
    const ushort_t hlo = f2bf(hn - bf2f(hhi));
    const int nbk = n0w + l31;
    hshi[nbk * 18 + jl] = hhi;
    hslo[nbk * 18 + jl] = hlo;
  }
  __syncthreads();

  // coalesced h-plane write (B,H): 4 threads/row x 8B
  {
    const int nbk = tid >> 2;
    const int jq = (tid & 3) * 4;
    ushort4 vh, vl;
    vh.x = hshi[nbk * 18 + jq + 0]; vh.y = hshi[nbk * 18 + jq + 1];
    vh.z = hshi[nbk * 18 + jq + 2]; vh.w = hshi[nbk * 18 + jq + 3];
    vl.x = hslo[nbk * 18 + jq + 0]; vl.y = hslo[nbk * 18 + jq + 1];
    vl.z = hslo[nbk * 18 + jq + 2]; vl.w = hslo[nbk * 18 + jq + 3];
    *(ushort4*)&U.Hhi[(size_t)(n0blk + nbk) * kH + jt0 + jq] = vh;
    *(ushort4*)&U.Hlo[(size_t)(n0blk + nbk) * kH + jt0 + jq] = vl;
  }

  if (isB) {
    if (P.do_head && tid < 64) {
      float s = 0.0f;
      #pragma unroll
      for (int jb = 0; jb < 16; ++jb)
        s += (bf2f(hshi[tid * 18 + jb]) + bf2f(hslo[tid * 18 + jb])) * P.headW[jt0 + jb];
      atomicAdd(&P.head_acc[n0blk + tid], s);
    }
  } else if (mb == 0 && tid < 64) {
    const int n = n0blk + tid;
    if (P.do_init) P.inp_next[n] = P.headb[0];
    if (P.ocol >= 0) P.outp[(size_t)n * kHor + P.ocol] = P.xsrc[n];
  }
}

// ---- prep kernels ----
__global__ void prep_w(const float* __restrict__ s0, const float* __restrict__ s1,
                       ushort_t* __restrict__ hi, ushort_t* __restrict__ lo, int Kw) {
  const int k = blockIdx.x * 256 + threadIdx.x;
  const int r = blockIdx.y;                 // packed row j*4+g
  const int j = r >> 2, g = r & 3;
  const int srow = g * kH + j;
  const float v = (k < kH) ? s0[(size_t)srow * kH + k]
                           : s1[(size_t)srow * kH + (k - kH)];
  const ushort_t h = f2bf(v);
  const ushort_t l = f2bf(v - bf2f(h));
  hi[(size_t)r * Kw + k] = h;
  lo[(size_t)r * Kw + k] = l;
}

__global__ void prep_vec(const float* __restrict__ src, float* __restrict__ dst) {
  const int t = blockIdx.x * 256 + threadIdx.x;   // 2048
  const int j = t >> 2, g = t & 3;
  dst[t] = src[g * kH + j];
}

__global__ void init_zero(ushort_t* p0, ushort_t* p1, ushort_t* p2, ushort_t* p3,
                          ushort_t* p4, ushort_t* p5, ushort_t* p6, ushort_t* p7,
                          float* c0, float* c1) {
  const int i = blockIdx.x * 256 + threadIdx.x;   // 262144
  p0[i] = 0; p1[i] = 0; p2[i] = 0; p3[i] = 0;
  p4[i] = 0; p5[i] = 0; p6[i] = 0; p7[i] = 0;
  c0[i] = 0.0f; c1[i] = 0.0f;
}

__global__ void out_last(const float* __restrict__ ib, float* __restrict__ out) {
  const int n = blockIdx.x * 256 + threadIdx.x;
  out[(size_t)n * kHor + 63] = ib[n];
}

extern "C" void kernel_launch(void* const* d_in, const int* in_sizes, int n_in,
                              void* d_out, int out_size, void* d_ws, size_t ws_size,
                              hipStream_t stream) {
  const float* x     = (const float*)d_in[0];
  const float* eWih0 = (const float*)d_in[1];
  const float* eWhh0 = (const float*)d_in[2];
  const float* eb0   = (const float*)d_in[3];
  const float* eWih1 = (const float*)d_in[4];
  const float* eWhh1 = (const float*)d_in[5];
  const float* eb1   = (const float*)d_in[6];
  const float* dWih0 = (const float*)d_in[7];
  const float* dWhh0 = (const float*)d_in[8];
  const float* db0   = (const float*)d_in[9];
  const float* dWih1 = (const float*)d_in[10];
  const float* dWhh1 = (const float*)d_in[11];
  const float* db1   = (const float*)d_in[12];
  const float* hW    = (const float*)d_in[13];
  const float* hb    = (const float*)d_in[14];
  float* out = (float*)d_out;

  char* w = (char*)d_ws;
  size_t off = 0;
  auto aus = [&](size_t n) { ushort_t* p = (ushort_t*)(w + off); off += ((n * 2 + 255) & ~(size_t)255); return p; };
  auto afl = [&](size_t n) { float* p = (float*)(w + off); off += ((n * 4 + 255) & ~(size_t)255); return p; };

  ushort_t* w0e_hi = aus((size_t)NG * 512); ushort_t* w0e_lo = aus((size_t)NG * 512);
  ushort_t* w1e_hi = aus((size_t)NG * 1024); ushort_t* w1e_lo = aus((size_t)NG * 1024);
  ushort_t* w0d_hi = aus((size_t)NG * 512); ushort_t* w0d_lo = aus((size_t)NG * 512);
  ushort_t* w1d_hi = aus((size_t)NG * 1024); ushort_t* w1d_lo = aus((size_t)NG * 1024);
  ushort_t* h0hi[2] = {aus(kB * kH), aus(kB * kH)};
  ushort_t* h0lo[2] = {aus(kB * kH), aus(kB * kH)};
  ushort_t* h1hi[2] = {aus(kB * kH), aus(kB * kH)};
  ushort_t* h1lo[2] = {aus(kB * kH), aus(kB * kH)};
  float* c0 = afl((size_t)kH * kB);
  float* c1 = afl((size_t)kH * kB);
  float* be0 = afl(NG); float* be1 = afl(NG);
  float* bd0 = afl(NG); float* bd1 = afl(NG);
  float* wxe = afl(NG); float* wxd = afl(NG);
  float* ib[2] = {afl(kB), afl(kB)};

  prep_w<<<dim3(2, NG), 256, 0, stream>>>(eWhh0, eWhh0, w0e_hi, w0e_lo, 512);
  prep_w<<<dim3(4, NG), 256, 0, stream>>>(eWih1, eWhh1, w1e_hi, w1e_lo, 1024);
  prep_w<<<dim3(2, NG), 256, 0, stream>>>(dWhh0, dWhh0, w0d_hi, w0d_lo, 512);
  prep_w<<<dim3(4, NG), 256, 0, stream>>>(dWih1, dWhh1, w1d_hi, w1d_lo, 1024);
  prep_vec<<<8, 256, 0, stream>>>(eb0, be0);
  prep_vec<<<8, 256, 0, stream>>>(eb1, be1);
  prep_vec<<<8, 256, 0, stream>>>(db0, bd0);
  prep_vec<<<8, 256, 0, stream>>>(db1, bd1);
  prep_vec<<<8, 256, 0, stream>>>(eWih0, wxe);
  prep_vec<<<8, 256, 0, stream>>>(dWih0, wxd);
  init_zero<<<1024, 256, 0, stream>>>(h0hi[0], h0hi[1], h0lo[0], h0lo[1],
                                      h1hi[0], h1hi[1], h1lo[0], h1lo[1], c0, c1);

  // ---------- encoder: wavefront phases p=0..256 (L0[p] || L1[p-1]) ----------
  for (int p = 0; p <= 256; ++p) {
    const bool hasA = p < 256, hasB = p >= 1;
    const int rd = p & 1, wr = (p + 1) & 1;
    KP P = {};
    P.nA = hasA ? 256 : 0;
    if (hasA) {
      P.ua = {w0e_hi, w0e_lo, h0hi[rd], h0lo[rd], h0hi[rd], h0lo[rd],
              be0, c0, h0hi[wr], h0lo[wr], 512};
      P.xsrc = x; P.wx = wxe; P.xmode = 0; P.tcol = p;
    }
    if (hasB) {
      P.ub = {w1e_hi, w1e_lo, h0hi[rd], h0lo[rd], h1hi[rd], h1lo[rd],
              be1, c1, h1hi[wr], h1lo[wr], 1024};
    }
    P.ocol = -1; P.headb = hb;
    const int grid = (hasA ? 256 : 0) + (hasB ? 256 : 0);
    lstm_mfma<<<grid, 256, 0, stream>>>(P);
  }
  // h0 final in planes[0], h1 final in planes[1]

  // ---------- decoder: serial, 2 launches/step ----------
  for (int t = 0; t < kHor; ++t) {
    const int r0 = t & 1, w0i = (t + 1) & 1;
    const int r1 = (t + 1) & 1, w1i = t & 1;
    float* ibr = ib[t & 1];
    float* ibw = ib[(t + 1) & 1];
    {
      KP P = {};
      P.nA = 256;
      P.ua = {w0d_hi, w0d_lo, h0hi[r0], h0lo[r0], h0hi[r0], h0lo[r0],
              bd0, c0, h0hi[w0i], h0lo[w0i], 512};
      P.wx = wxd;
      if (t == 0) { P.xsrc = x; P.xmode = 0; P.tcol = 255; P.ocol = -1; }
      else        { P.xsrc = ibr; P.xmode = 1; P.ocol = t - 1; P.outp = out; }
      P.do_init = 1; P.inp_next = ibw; P.headb = hb;
      lstm_mfma<<<256, 256, 0, stream>>>(P);
    }
    {
      KP P = {};
      P.nA = 0;
      P.ub = {w1d_hi, w1d_lo, h0hi[w0i], h0lo[w0i], h1hi[r1], h1lo[r1],
              bd1, c1, h1hi[w1i], h1lo[w1i], 1024};
      P.ocol = -1; P.headb = hb;
      P.do_head = 1; P.headW = hW; P.head_acc = ibw;
      lstm_mfma<<<256, 256, 0, stream>>>(P);
    }
  }
  // last head output: ib[(63+1)&1] = ib[0]
  out_last<<<2, 256, 0, stream>>>(ib[0], out);
}